// Round 4
// baseline (38.722 us; speedup 1.0000x reference)
//
#include <hip/hip_runtime.h>
#include <hip/hip_bf16.h>

// APELoss via moment-corrected histogram, 2 dispatches.
//
// K1: 16 hist blocks write per-block histogram segments (int count + fixed-point
//     first moment, converted to float at writeout; no global atomics, nothing
//     to zero) + per-block bg max; 256 fg-fg blocks do the exact F x F part;
//     block 0 zeroes K2's completion counter.
// K2: 256 eval blocks merge the 16 segments into LDS (fixed-order sum ->
//     deterministic), evaluate 4 fg rows each over 2048 bins with first-order
//     Taylor correction, publish per-row results with agent-scope stores
//     (per-XCD L2s are non-coherent; 16B row chunks share cache lines), then
//     last block (threadfence + atomicAdd) does the final reduce to the scalar.
//
// Math (log2 domain): dl = KC*(c - f), mask dl > -KC else -inf.
//   u = 2^dl, o = 1+u, rr = rcp(o): sigmoid = 1-rr, softplus/ln2 = log2(o)
//   d(sigmoid)/dv = LAMB*(1-rr)*rr ; d(softplus/ln2)/dv = KC*(1-rr)
// valid_i = (bg_max > f_i - 1) || fg_pos_count_i > 0.

#define APE_LAMB 4.0f
#define APE_KC   5.770780163555856f   // LAMB * log2(e)
#define APE_LN2  0.6931471805599453f
#define NINF     (-__builtin_inff())

__device__ __forceinline__ float exp2g(float x) { return __builtin_amdgcn_exp2f(x); }
__device__ __forceinline__ float log2g(float x) { return __builtin_amdgcn_logf(x); }
__device__ __forceinline__ float rcpg(float x)  { return __builtin_amdgcn_rcpf(x); }

constexpr int   B_BINS  = 2048;
constexpr int   NB      = 16;     // histogram segment blocks
constexpr int   TPB     = 256;
constexpr float BIN_LO  = -5.12f;
constexpr float BIN_DL  = 0.005f;
constexpr float BIN_INV = 200.0f;
constexpr float M1SCALE = 268435456.0f;             // 2^28
constexpr float M1INV   = 3.725290298461914e-09f;   // 2^-28
constexpr int   ROWS_E  = 4;      // fg rows per eval block
constexpr int   ROWS_B  = 4;      // fg rows per fg-fg block

#define ST_AGENT(p, v) __hip_atomic_store((p), (v), __ATOMIC_RELAXED, __HIP_MEMORY_SCOPE_AGENT)
#define LD_AGENT(p)    __hip_atomic_load((p), __ATOMIC_RELAXED, __HIP_MEMORY_SCOPE_AGENT)

// ---------------- K1: per-block histograms + bg max + fg-fg + ctr reset -----
__global__ __launch_bounds__(TPB) void ape_phase1(
    const float* __restrict__ logits, const float* __restrict__ ious,
    int F, int M, int chunkH,
    float* __restrict__ gC, float* __restrict__ gM, float* __restrict__ bmaxA,
    float* __restrict__ dist2, float* __restrict__ rank2, float* __restrict__ cnt2,
    int* __restrict__ ctr)
{
    const int tid  = threadIdx.x;
    const int lane = tid & 63, wid = tid >> 6;

    if (blockIdx.x == 0 && tid == 0) *ctr = 0;   // visible to K2 via kernel boundary

    if ((int)blockIdx.x < NB) {
        // ---- histogram of one bg slice ----
        __shared__ int hc[B_BINS];
        __shared__ int hm[B_BINS];
        for (int b = tid; b < B_BINS; b += TPB) { hc[b] = 0; hm[b] = 0; }
        __syncthreads();

        const float* bg = logits + F;
        const int start = (int)blockIdx.x * chunkH;
        const int end   = min(start + chunkH, M);
        float bmax = NINF;

        for (int j = start + tid * 4; j < end; j += TPB * 4) {
            float v[4];
            if (j + 4 <= end) {
                float4 q = *reinterpret_cast<const float4*>(bg + j);
                v[0] = q.x; v[1] = q.y; v[2] = q.z; v[3] = q.w;
            } else {
#pragma unroll
                for (int k = 0; k < 4; ++k) v[k] = (j + k < end) ? bg[j + k] : NINF;
            }
#pragma unroll
            for (int k = 0; k < 4; ++k) {
                if (j + k >= end) continue;
                float x = v[k];
                bmax = fmaxf(bmax, x);
                int b = (int)((x - BIN_LO) * BIN_INV);
                b = min(max(b, 0), B_BINS - 1);
                float c = fmaf((float)b, BIN_DL, BIN_LO + 0.5f * BIN_DL);
                int q = __float2int_rn((x - c) * M1SCALE);
                atomicAdd(&hc[b], 1);
                atomicAdd(&hm[b], q);
            }
        }
        __syncthreads();
        const int base = (int)blockIdx.x * B_BINS;
        for (int b = tid; b < B_BINS; b += TPB) {
            gC[base + b] = (float)hc[b];
            gM[base + b] = (float)hm[b] * M1INV;
        }
        __shared__ float rm[4];
        for (int off = 32; off > 0; off >>= 1) bmax = fmaxf(bmax, __shfl_down(bmax, off));
        if (lane == 0) rm[wid] = bmax;
        __syncthreads();
        if (tid == 0)
            bmaxA[blockIdx.x] = fmaxf(fmaxf(rm[0], rm[1]), fmaxf(rm[2], rm[3]));
    } else {
        // ---- fg-fg exact pairwise ----
        const int i0 = ((int)blockIdx.x - NB) * ROWS_B;
        float fgl[ROWS_B], ioui[ROWS_B];
#pragma unroll
        for (int r = 0; r < ROWS_B; ++r) {
            int i = i0 + r;
            fgl[r]  = (i < F) ? logits[i] * APE_KC : __builtin_inff();
            ioui[r] = (i < F) ? ious[i] : 0.f;
        }
        float dist[ROWS_B], rank[ROWS_B], cnt[ROWS_B];
#pragma unroll
        for (int r = 0; r < ROWS_B; ++r) { dist[r]=0.f; rank[r]=0.f; cnt[r]=0.f; }

        for (int j = tid; j < F; j += TPB) {
            float fjl  = logits[j] * APE_KC;
            float iouj = ious[j];
#pragma unroll
            for (int r = 0; r < ROWS_B; ++r) {
                float dl = fjl - fgl[r];
                bool above = dl > -APE_KC;
                float dm = above ? dl : NINF;
                float u  = exp2g(dm);
                float o  = 1.0f + u;
                float sig = 1.0f - rcpg(o);
                float spl = log2g(o);
                bool pos = iouj < ioui[r];
                rank[r] += sig;
                dist[r] += pos ? spl : 0.f;
                cnt[r]  += (above && pos) ? 1.f : 0.f;
            }
        }
        __shared__ float redf[4][ROWS_B * 3];
#pragma unroll
        for (int r = 0; r < ROWS_B; ++r) {
            float d = dist[r], a = rank[r], c = cnt[r];
            for (int off = 32; off > 0; off >>= 1) {
                d += __shfl_down(d, off);
                a += __shfl_down(a, off);
                c += __shfl_down(c, off);
            }
            if (lane == 0) { redf[wid][r*3+0]=d; redf[wid][r*3+1]=a; redf[wid][r*3+2]=c; }
        }
        __syncthreads();
        if (tid < ROWS_B * 3) {
            float sum = redf[0][tid] + redf[1][tid] + redf[2][tid] + redf[3][tid];
            int r = tid / 3, q = tid % 3;
            int i = i0 + r;
            if (i < F) {
                if      (q == 0) dist2[i] = sum;
                else if (q == 1) rank2[i] = sum;
                else             cnt2[i]  = sum;
            }
        }
    }
}

// ---------------- K2: merge+eval per row, last block finalizes --------------
__global__ __launch_bounds__(TPB) void ape_phase2(
    const float* __restrict__ logits, const float* __restrict__ ious, int F, int EB,
    const float* __restrict__ gC, const float* __restrict__ gM,
    const float* __restrict__ bmaxA,
    const float* __restrict__ dist2, const float* __restrict__ rank2,
    const float* __restrict__ cnt2,
    float* __restrict__ rankB, float* __restrict__ distB,
    int* __restrict__ ctr, float* __restrict__ out)
{
    const int tid  = threadIdx.x;
    const int lane = tid & 63, wid = tid >> 6;

    // merge 16 segments into LDS (fixed order -> deterministic)
    __shared__ float2 h[B_BINS];
    for (int b = tid; b < B_BINS; b += TPB) {
        float c = 0.f, m = 0.f;
#pragma unroll
        for (int s = 0; s < NB; ++s) {
            c += gC[s * B_BINS + b];
            m += gM[s * B_BINS + b];
        }
        h[b] = make_float2(c, m);
    }

    const int i0 = (int)blockIdx.x * ROWS_E;
    float fKC[ROWS_E];
#pragma unroll
    for (int r = 0; r < ROWS_E; ++r) {
        int i = i0 + r;
        fKC[r] = (i < F) ? logits[i] * APE_KC : __builtin_inff();
    }
    __syncthreads();

    float rk[ROWS_E], dt[ROWS_E];
#pragma unroll
    for (int r = 0; r < ROWS_E; ++r) { rk[r] = 0.f; dt[r] = 0.f; }

    for (int it = 0; it < B_BINS; it += TPB) {
        const int b = it + tid;
        float2 cm = h[b];
        float cKC  = fmaf((float)b, BIN_DL * APE_KC, (BIN_LO + 0.5f * BIN_DL) * APE_KC);
        float m1x4 = cm.y * APE_LAMB;
        float m1kc = cm.y * APE_KC;
#pragma unroll
        for (int r = 0; r < ROWS_E; ++r) {
            float dl = cKC - fKC[r];
            float dm = (dl > -APE_KC) ? dl : NINF;
            float u  = exp2g(dm);
            float o  = 1.0f + u;
            float rr = rcpg(o);
            float lg = log2g(o);
            float s  = 1.0f - rr;
            rk[r] = fmaf(cm.x, s,  rk[r]);
            rk[r] = fmaf(m1x4, s * rr, rk[r]);
            dt[r] = fmaf(cm.x, lg, dt[r]);
            dt[r] = fmaf(m1kc, s,  dt[r]);
        }
    }

    __shared__ float red[4][ROWS_E * 2];
#pragma unroll
    for (int r = 0; r < ROWS_E; ++r) {
        float a = rk[r], d = dt[r];
        for (int off = 32; off > 0; off >>= 1) {
            a += __shfl_down(a, off);
            d += __shfl_down(d, off);
        }
        if (lane == 0) { red[wid][r*2+0] = a; red[wid][r*2+1] = d; }
    }
    __syncthreads();
    if (tid < ROWS_E * 2) {
        float sum = red[0][tid] + red[1][tid] + red[2][tid] + red[3][tid];
        int r = tid >> 1, q = tid & 1;
        int i = i0 + r;
        if (i < F) {
            if (q == 0) ST_AGENT(&rankB[i], sum);   // agent scope: cross-XCD L2s
            else        ST_AGENT(&distB[i], sum);   // are not coherent
        }
    }
    __syncthreads();

    // last-block finalize
    __shared__ int lastFlag;
    if (tid == 0) {
        __threadfence();
        int old = atomicAdd(ctr, 1);
        lastFlag = (old == EB - 1) ? 1 : 0;
    }
    __syncthreads();
    if (!lastFlag) return;
    __threadfence();

    __shared__ float gms;
    if (tid == 0) {
        float m = NINF;
        for (int k = 0; k < NB; ++k) m = fmaxf(m, bmaxA[k]);
        gms = m;
    }
    __syncthreads();
    const float gmax = gms;

    float sper = 0.f, sval = 0.f;
    for (int i = tid; i < F; i += TPB) {
        float rkv = LD_AGENT(&rankB[i]) + rank2[i];
        float dtv = (LD_AGENT(&distB[i]) + dist2[i]) * APE_LN2;
        bool valid = (gmax > logits[i] - 1.0f) || (cnt2[i] > 0.f);
        if (valid) {
            sper += dtv * ious[i] / rkv;
            sval += 1.f;
        }
    }
    __shared__ float rp[4], rv[4];
    for (int off = 32; off > 0; off >>= 1) {
        sper += __shfl_down(sper, off);
        sval += __shfl_down(sval, off);
    }
    if (lane == 0) { rp[wid] = sper; rv[wid] = sval; }
    __syncthreads();
    if (tid == 0) {
        float p = rp[0] + rp[1] + rp[2] + rp[3];
        float v = rv[0] + rv[1] + rv[2] + rv[3];
        out[0] = p / fmaxf(v, 1.f) / APE_LAMB;
    }
}

extern "C" void kernel_launch(void* const* d_in, const int* in_sizes, int n_in,
                              void* d_out, int out_size, void* d_ws, size_t ws_size,
                              hipStream_t stream) {
    const float* logits = (const float*)d_in[0];
    const float* ious   = (const float*)d_in[2];
    const int N = in_sizes[0];
    const int F = in_sizes[2];
    const int M = N - F;

    float* ws    = (float*)d_ws;
    float* gC    = ws;                       // [NB][B_BINS]
    float* gM    = gC + NB * B_BINS;         // [NB][B_BINS]
    float* bmaxA = gM + NB * B_BINS;         // [NB]
    float* rankB = bmaxA + NB;               // [F]
    float* distB = rankB + F;                // [F]
    float* dist2 = distB + F;                // [F]
    float* rank2 = dist2 + F;                // [F]
    float* cnt2  = rank2 + F;                // [F]
    int*   ctr   = (int*)(cnt2 + F);         // [1]

    int chunkH = ((M + NB - 1) / NB + 3) & ~3;
    if (chunkH < 4) chunkH = 4;

    const int FB = (F + ROWS_B - 1) / ROWS_B;
    const int EB = (F + ROWS_E - 1) / ROWS_E;

    ape_phase1<<<NB + FB, TPB, 0, stream>>>(logits, ious, F, M, chunkH,
                                            gC, gM, bmaxA, dist2, rank2, cnt2, ctr);
    ape_phase2<<<EB, TPB, 0, stream>>>(logits, ious, F, EB, gC, gM, bmaxA,
                                       dist2, rank2, cnt2, rankB, distB, ctr,
                                       (float*)d_out);
}

// Round 5
// 23.880 us; speedup vs baseline: 1.6215x; 1.6215x over previous
//
#include <hip/hip_runtime.h>
#include <hip/hip_bf16.h>

// APELoss via moment-corrected histogram, 2 dispatches, fence-free finalize.
//
// K1 (NB hist blocks + F/4 fg-fg blocks):
//   - hist blocks: per-block histogram segment of a bg slice (LDS int count +
//     2^28 fixed-point first moment -> float at writeout; no global atomics,
//     nothing to zero) + per-block bg max. Block 0 zeroes K2's counter.
//   - fg-fg blocks: exact F x F part (dist2/rank2/cnt2 per row).
// K2 (EB = F/4 eval blocks): merge NB segments into LDS (fixed order ->
//   deterministic), evaluate 4 rows over B_BINS bins with first-order Taylor,
//   combine with fg-fg partials + validity (bg max) into a per-block partial
//   (sper,sval). Publish partial with agent-scope (sc0 sc1, L2-bypassing)
//   stores, order with s_waitcnt vmcnt(0) (NO __threadfence -- a per-block
//   agent fence implies an L2 writeback on multi-XCD and cost ~20us in R4),
//   then relaxed agent atomicAdd(ctr); the block seeing EB-1 reduces the 2*EB
//   partials (fixed order -> deterministic) and writes the scalar.
//
// Math (log2 domain): dl = KC*(c - f), mask dl > -KC else -inf.
//   u = 2^dl, o = 1+u, rr = rcp(o): sigmoid = 1-rr, softplus/ln2 = log2(o)
//   d(sigmoid)/dv = LAMB*(1-rr)*rr ; d(softplus/ln2)/dv = KC*(1-rr)
// valid_i = (bg_max > f_i - 1) || fg_pos_count_i > 0.

#define APE_LAMB 4.0f
#define APE_KC   5.770780163555856f   // LAMB * log2(e)
#define APE_LN2  0.6931471805599453f
#define NINF     (-__builtin_inff())

__device__ __forceinline__ float exp2g(float x) { return __builtin_amdgcn_exp2f(x); }
__device__ __forceinline__ float log2g(float x) { return __builtin_amdgcn_logf(x); }
__device__ __forceinline__ float rcpg(float x)  { return __builtin_amdgcn_rcpf(x); }

constexpr int   B_BINS  = 1024;
constexpr int   NB      = 8;      // histogram segment blocks
constexpr int   TPB     = 256;
constexpr float BIN_LO  = -5.12f;
constexpr float BIN_DL  = 0.01f;
constexpr float BIN_INV = 100.0f;
constexpr float M1SCALE = 268435456.0f;             // 2^28
constexpr float M1INV   = 3.725290298461914e-09f;   // 2^-28
constexpr int   ROWS_E  = 4;      // fg rows per eval block
constexpr int   ROWS_B  = 4;      // fg rows per fg-fg block

#define ST_AGENT(p, v) __hip_atomic_store((p), (v), __ATOMIC_RELAXED, __HIP_MEMORY_SCOPE_AGENT)
#define LD_AGENT(p)    __hip_atomic_load((p), __ATOMIC_RELAXED, __HIP_MEMORY_SCOPE_AGENT)

// ---------------- K1: hist segments + bg max + fg-fg + ctr reset ------------
__global__ __launch_bounds__(TPB) void ape_phase1(
    const float* __restrict__ logits, const float* __restrict__ ious,
    int F, int M, int chunkH,
    float* __restrict__ gC, float* __restrict__ gM, float* __restrict__ bmaxA,
    float* __restrict__ dist2, float* __restrict__ rank2, float* __restrict__ cnt2,
    int* __restrict__ ctr)
{
    const int tid  = threadIdx.x;
    const int lane = tid & 63, wid = tid >> 6;

    if (blockIdx.x == 0 && tid == 0) *ctr = 0;   // visible to K2 via kernel boundary

    if ((int)blockIdx.x < NB) {
        // ---- histogram of one bg slice ----
        __shared__ int hc[B_BINS];
        __shared__ int hm[B_BINS];
        for (int b = tid; b < B_BINS; b += TPB) { hc[b] = 0; hm[b] = 0; }
        __syncthreads();

        const float* bg = logits + F;
        const int start = (int)blockIdx.x * chunkH;
        const int end   = min(start + chunkH, M);
        float bmax = NINF;

        for (int j = start + tid * 4; j < end; j += TPB * 4) {
            float v[4];
            if (j + 4 <= end) {
                float4 q = *reinterpret_cast<const float4*>(bg + j);
                v[0] = q.x; v[1] = q.y; v[2] = q.z; v[3] = q.w;
            } else {
#pragma unroll
                for (int k = 0; k < 4; ++k) v[k] = (j + k < end) ? bg[j + k] : NINF;
            }
#pragma unroll
            for (int k = 0; k < 4; ++k) {
                if (j + k >= end) continue;
                float x = v[k];
                bmax = fmaxf(bmax, x);
                int b = (int)((x - BIN_LO) * BIN_INV);
                b = min(max(b, 0), B_BINS - 1);
                float c = fmaf((float)b, BIN_DL, BIN_LO + 0.5f * BIN_DL);
                int q = __float2int_rn((x - c) * M1SCALE);
                atomicAdd(&hc[b], 1);
                atomicAdd(&hm[b], q);
            }
        }
        __syncthreads();
        const int base = (int)blockIdx.x * B_BINS;
        for (int b = tid; b < B_BINS; b += TPB) {
            gC[base + b] = (float)hc[b];
            gM[base + b] = (float)hm[b] * M1INV;   // logit units
        }
        __shared__ float rm[4];
        for (int off = 32; off > 0; off >>= 1) bmax = fmaxf(bmax, __shfl_down(bmax, off));
        if (lane == 0) rm[wid] = bmax;
        __syncthreads();
        if (tid == 0)
            bmaxA[blockIdx.x] = fmaxf(fmaxf(rm[0], rm[1]), fmaxf(rm[2], rm[3]));
    } else {
        // ---- fg-fg exact pairwise ----
        const int i0 = ((int)blockIdx.x - NB) * ROWS_B;
        float fgl[ROWS_B], ioui[ROWS_B];
#pragma unroll
        for (int r = 0; r < ROWS_B; ++r) {
            int i = i0 + r;
            fgl[r]  = (i < F) ? logits[i] * APE_KC : __builtin_inff();
            ioui[r] = (i < F) ? ious[i] : 0.f;
        }
        float dist[ROWS_B], rank[ROWS_B], cnt[ROWS_B];
#pragma unroll
        for (int r = 0; r < ROWS_B; ++r) { dist[r]=0.f; rank[r]=0.f; cnt[r]=0.f; }

        for (int j = tid; j < F; j += TPB) {
            float fjl  = logits[j] * APE_KC;
            float iouj = ious[j];
#pragma unroll
            for (int r = 0; r < ROWS_B; ++r) {
                float dl = fjl - fgl[r];
                bool above = dl > -APE_KC;
                float dm = above ? dl : NINF;
                float u  = exp2g(dm);
                float o  = 1.0f + u;
                float sig = 1.0f - rcpg(o);
                float spl = log2g(o);
                bool pos = iouj < ioui[r];
                rank[r] += sig;
                dist[r] += pos ? spl : 0.f;
                cnt[r]  += (above && pos) ? 1.f : 0.f;
            }
        }
        __shared__ float redf[4][ROWS_B * 3];
#pragma unroll
        for (int r = 0; r < ROWS_B; ++r) {
            float d = dist[r], a = rank[r], c = cnt[r];
            for (int off = 32; off > 0; off >>= 1) {
                d += __shfl_down(d, off);
                a += __shfl_down(a, off);
                c += __shfl_down(c, off);
            }
            if (lane == 0) { redf[wid][r*3+0]=d; redf[wid][r*3+1]=a; redf[wid][r*3+2]=c; }
        }
        __syncthreads();
        if (tid < ROWS_B * 3) {
            float sum = redf[0][tid] + redf[1][tid] + redf[2][tid] + redf[3][tid];
            int r = tid / 3, q = tid % 3;
            int i = i0 + r;
            if (i < F) {
                if      (q == 0) dist2[i] = sum;
                else if (q == 1) rank2[i] = sum;
                else             cnt2[i]  = sum;
            }
        }
    }
}

// ---------------- K2: merge + eval + per-block partial + last-block final ---
__global__ __launch_bounds__(TPB) void ape_phase2(
    const float* __restrict__ logits, const float* __restrict__ ious, int F, int EB,
    const float* __restrict__ gC, const float* __restrict__ gM,
    const float* __restrict__ bmaxA,
    const float* __restrict__ dist2, const float* __restrict__ rank2,
    const float* __restrict__ cnt2,
    float* __restrict__ pp, float* __restrict__ pv,
    int* __restrict__ ctr, float* __restrict__ out)
{
    const int tid  = threadIdx.x;
    const int lane = tid & 63, wid = tid >> 6;

    // merge NB segments into LDS (fixed order -> deterministic)
    __shared__ float2 h[B_BINS];
    for (int b = tid; b < B_BINS; b += TPB) {
        float c = 0.f, m = 0.f;
#pragma unroll
        for (int s = 0; s < NB; ++s) {
            c += gC[s * B_BINS + b];
            m += gM[s * B_BINS + b];
        }
        h[b] = make_float2(c, m);
    }

    const int i0 = (int)blockIdx.x * ROWS_E;
    float fKC[ROWS_E];
#pragma unroll
    for (int r = 0; r < ROWS_E; ++r) {
        int i = i0 + r;
        fKC[r] = (i < F) ? logits[i] * APE_KC : __builtin_inff();
    }
    __syncthreads();

    float rk[ROWS_E], dt[ROWS_E];
#pragma unroll
    for (int r = 0; r < ROWS_E; ++r) { rk[r] = 0.f; dt[r] = 0.f; }

    for (int it = 0; it < B_BINS; it += TPB) {
        const int b = it + tid;
        float2 cm = h[b];
        float cKC  = fmaf((float)b, BIN_DL * APE_KC, (BIN_LO + 0.5f * BIN_DL) * APE_KC);
        float m1x4 = cm.y * APE_LAMB;
        float m1kc = cm.y * APE_KC;
#pragma unroll
        for (int r = 0; r < ROWS_E; ++r) {
            float dl = cKC - fKC[r];
            float dm = (dl > -APE_KC) ? dl : NINF;
            float u  = exp2g(dm);
            float o  = 1.0f + u;
            float rr = rcpg(o);
            float lg = log2g(o);
            float s  = 1.0f - rr;
            rk[r] = fmaf(cm.x, s,  rk[r]);
            rk[r] = fmaf(m1x4, s * rr, rk[r]);
            dt[r] = fmaf(cm.x, lg, dt[r]);
            dt[r] = fmaf(m1kc, s,  dt[r]);
        }
    }

    __shared__ float red[4][ROWS_E * 2];
#pragma unroll
    for (int r = 0; r < ROWS_E; ++r) {
        float a = rk[r], d = dt[r];
        for (int off = 32; off > 0; off >>= 1) {
            a += __shfl_down(a, off);
            d += __shfl_down(d, off);
        }
        if (lane == 0) { red[wid][r*2+0] = a; red[wid][r*2+1] = d; }
    }
    __syncthreads();

    // per-block partial of the final sum, published fence-free
    __shared__ int lastFlag;
    if (tid == 0) {
        float gmax = NINF;
#pragma unroll
        for (int k = 0; k < NB; ++k) gmax = fmaxf(gmax, bmaxA[k]);
        float sper = 0.f, sval = 0.f;
#pragma unroll
        for (int r = 0; r < ROWS_E; ++r) {
            int i = i0 + r;
            if (i < F) {
                float rowRank = red[0][r*2+0] + red[1][r*2+0] + red[2][r*2+0] + red[3][r*2+0];
                float rowDist = red[0][r*2+1] + red[1][r*2+1] + red[2][r*2+1] + red[3][r*2+1];
                float rkv = rowRank + rank2[i];
                float dtv = (rowDist + dist2[i]) * APE_LN2;
                bool valid = (gmax > logits[i] - 1.0f) || (cnt2[i] > 0.f);
                if (valid) {
                    sper += dtv * ious[i] / rkv;
                    sval += 1.f;
                }
            }
        }
        ST_AGENT(&pp[blockIdx.x], sper);   // sc0 sc1: bypass L2, land at LLC
        ST_AGENT(&pv[blockIdx.x], sval);
        asm volatile("s_waitcnt vmcnt(0)" ::: "memory");  // stores complete at LLC
        int old = __hip_atomic_fetch_add(ctr, 1, __ATOMIC_RELAXED,
                                         __HIP_MEMORY_SCOPE_AGENT);
        lastFlag = (old == EB - 1) ? 1 : 0;
    }
    __syncthreads();
    if (!lastFlag) return;

    // last block: deterministic fixed-order reduce of the partials
    float sp = 0.f, sv = 0.f;
    for (int k = tid; k < EB; k += TPB) {
        sp += LD_AGENT(&pp[k]);
        sv += LD_AGENT(&pv[k]);
    }
    __shared__ float rp[4], rv[4];
    for (int off = 32; off > 0; off >>= 1) {
        sp += __shfl_down(sp, off);
        sv += __shfl_down(sv, off);
    }
    if (lane == 0) { rp[wid] = sp; rv[wid] = sv; }
    __syncthreads();
    if (tid == 0) {
        float p = rp[0] + rp[1] + rp[2] + rp[3];
        float v = rv[0] + rv[1] + rv[2] + rv[3];
        out[0] = p / fmaxf(v, 1.f) / APE_LAMB;
    }
}

extern "C" void kernel_launch(void* const* d_in, const int* in_sizes, int n_in,
                              void* d_out, int out_size, void* d_ws, size_t ws_size,
                              hipStream_t stream) {
    const float* logits = (const float*)d_in[0];
    const float* ious   = (const float*)d_in[2];
    const int N = in_sizes[0];
    const int F = in_sizes[2];
    const int M = N - F;

    const int FB = (F + ROWS_B - 1) / ROWS_B;
    const int EB = (F + ROWS_E - 1) / ROWS_E;

    float* ws    = (float*)d_ws;
    float* gC    = ws;                       // [NB][B_BINS]
    float* gM    = gC + NB * B_BINS;         // [NB][B_BINS]
    float* bmaxA = gM + NB * B_BINS;         // [NB]
    float* dist2 = bmaxA + NB;               // [F]
    float* rank2 = dist2 + F;                // [F]
    float* cnt2  = rank2 + F;                // [F]
    float* pp    = cnt2 + F;                 // [EB]
    float* pv    = pp + EB;                  // [EB]
    int*   ctr   = (int*)(pv + EB);          // [1]

    int chunkH = ((M + NB - 1) / NB + 3) & ~3;
    if (chunkH < 4) chunkH = 4;

    ape_phase1<<<NB + FB, TPB, 0, stream>>>(logits, ious, F, M, chunkH,
                                            gC, gM, bmaxA, dist2, rank2, cnt2, ctr);
    ape_phase2<<<EB, TPB, 0, stream>>>(logits, ious, F, EB, gC, gM, bmaxA,
                                       dist2, rank2, cnt2, pp, pv, ctr,
                                       (float*)d_out);
}